// Round 15
// baseline (94.363 us; speedup 1.0000x reference)
//
#include <hip/hip_runtime.h>

#define NROWS 2048
#define KDIM  768
#define L     40
#define HN    (NROWS * L)   // 81920 floats per h matrix

#define OPB   5     // o per block (40 / 8 o-groups)  -- LDS <= 20KB for 8 blk/CU
#define RPB   16    // rows per block
#define SEGS  16    // k-segments per row (48 k each)
#define SF4   12    // float4 per seg (2 chunks of 6)
#define SP4   13    // padded seg stride in LDS f4 (proven 2-way-free, R12)

// ---------------------------------------------------------------------------
// Kernel 1 (v10): 8 WAVES/SIMD -- the one lever with measured positive slope.
// TLP trajectory: 1 w/SIMD (R6) = 99us -> 4 w/SIMD (R7/R12/R13/R14) = 36-41us
// regardless of locality/burst/LDS structure (all those theories falsified).
// Exposed memory latency at fixed TLP fits: ~70% stall, no pipe saturated
// (R10 PMC). Here: 2048 blocks x 256 thr = 8 blocks/CU = 32 waves/CU
// = 8 waves/SIMD (hw max). launch_bounds(256,8) caps VGPR 64: A loaded in
// 2x 6-f4 chunks (24 regs). W tile 5 o x 768 k, SEGS=16/SP4=13 padded
// layout (2-way bank = free, proven R12). XCD grouping kept: 16 replicas
// (8 og x 2 which) of each rowblock share XCD; per-XCD set 1.75MB < L2.
// ---------------------------------------------------------------------------
__global__ __launch_bounds__(256, 8) void k_proj(const float* __restrict__ x,
                                                 const float* __restrict__ y,
                                                 const float* __restrict__ W1,
                                                 const float* __restrict__ b1,
                                                 float* __restrict__ hxb,
                                                 float* __restrict__ hy) {
    const int bid = blockIdx.x;          // 0..2047
    const int c   = bid & 7;             // XCD (round-robin mapping)
    const int t   = bid >> 3;            // 0..255
    const int j   = t & 15;              // replica: og*2+which
    const int q   = t >> 4;              // 0..15
    const int rb  = q * 8 + c;           // rowblock 0..127
    const int og    = j >> 1;            // 0..7
    const int which = j & 1;

    const float* __restrict__ A = which ? y : x;
    const int tid = threadIdx.x;
    const int s   = tid & 15;            // 0..15 k-segment (48 k each)
    const int r   = tid >> 4;            // 0..15 row within block
    const int row0 = rb * RPB;
    const int o0   = og * OPB;

    __shared__ float4 wlds[OPB * SEGS * SP4];   // 1040 f4 = 16.6 KB

    // ---- stage W tile (5 rows x 192 f4, padded seg layout) ----
    const float4* W1f4 = (const float4*)W1;          // 384 f4 per W1 row
    for (int i = tid; i < OPB * 192; i += 256) {
        int ol = i / 192, qq = i - ol * 192;
        int ss = qq / SF4, jj = qq - ss * SF4;
        wlds[(ol * SEGS + ss) * SP4 + jj] =
            W1f4[(size_t)(o0 + ol) * 384 + which * 192 + qq];
    }

    const float4* arow = (const float4*)(A + (size_t)(row0 + r) * KDIM) + s * SF4;

    float acc[OPB];
#pragma unroll
    for (int ol = 0; ol < OPB; ++ol) acc[ol] = 0.f;

    // first A chunk can overlap staging
    float4 a[6];
#pragma unroll
    for (int jj = 0; jj < 6; ++jj) a[jj] = arow[jj];
    __syncthreads();

    // ---- chunk 0 ----
#pragma unroll
    for (int ol = 0; ol < OPB; ++ol) {
        const float4* wp = &wlds[(ol * SEGS + s) * SP4];
        float sacc = 0.f;
#pragma unroll
        for (int jj = 0; jj < 6; ++jj) {
            float4 w = wp[jj];
            sacc += a[jj].x * w.x + a[jj].y * w.y
                  + a[jj].z * w.z + a[jj].w * w.w;
        }
        acc[ol] += sacc;
    }
    // ---- chunk 1 ----
#pragma unroll
    for (int jj = 0; jj < 6; ++jj) a[jj] = arow[6 + jj];
#pragma unroll
    for (int ol = 0; ol < OPB; ++ol) {
        const float4* wp = &wlds[(ol * SEGS + s) * SP4 + 6];
        float sacc = 0.f;
#pragma unroll
        for (int jj = 0; jj < 6; ++jj) {
            float4 w = wp[jj];
            sacc += a[jj].x * w.x + a[jj].y * w.y
                  + a[jj].z * w.z + a[jj].w * w.w;
        }
        acc[ol] += sacc;
    }

    // ---- cross-seg reduce via padded LDS transpose ----
    __syncthreads();
    float* red = (float*)wlds;                  // 5*16*17 = 1360 floats
#pragma unroll
    for (int ol = 0; ol < OPB; ++ol)
        red[(ol * SEGS + s) * 17 + r] = acc[ol];
    __syncthreads();

    if (tid < RPB * OPB) {                       // 80 outputs
        int rr = tid / OPB, ol = tid - rr * OPB;
        float v = 0.f;
#pragma unroll
        for (int ss = 0; ss < SEGS; ++ss)
            v += red[(ol * SEGS + ss) * 17 + rr];
        int o = o0 + ol;
        if (!which) {
            hxb[(size_t)(row0 + rr) * L + o] = v + b1[o];
        } else {
            hy[(size_t)(row0 + rr) * L + o] = v;
        }
    }
}

// ---------------------------------------------------------------------------
// Kernel 2: pairwise sum of exp(T_ij - 1) + diagonal T0 sum.  (verified)
// ---------------------------------------------------------------------------
#define BI 128
#define BJ 64
#define STRD 44

__global__ __launch_bounds__(512, 4) void k_pair(const float* __restrict__ hxb,
                                                 const float* __restrict__ hy,
                                                 const float* __restrict__ W2,
                                                 const float* __restrict__ b2p,
                                                 float* __restrict__ pairE,
                                                 float* __restrict__ pairT) {
    __shared__ float shy[BI * STRD];
    __shared__ float shx[BJ * STRD];
    __shared__ float sw2[STRD];
    __shared__ float red[16];

    const int tid = threadIdx.x;
    const int i0 = blockIdx.x * BI;
    const int j0 = blockIdx.y * BJ;

    for (int idx = tid; idx < BI * 10; idx += 512) {
        int rr = idx / 10, cc = idx - rr * 10;
        float4 v = ((const float4*)(hy + (size_t)i0 * L))[idx];
        *(float4*)(shy + rr * STRD + cc * 4) = v;
    }
    for (int idx = tid; idx < BJ * 10; idx += 512) {
        int rr = idx / 10, cc = idx - rr * 10;
        float4 v = ((const float4*)(hxb + (size_t)j0 * L))[idx];
        *(float4*)(shx + rr * STRD + cc * 4) = v;
    }
    if (tid < 10) ((float4*)sw2)[tid] = ((const float4*)W2)[tid];
    __syncthreads();

    const int tx = tid & 15, ty = tid >> 4;   // ty 0..31

    float acc[4][4];
#pragma unroll
    for (int u = 0; u < 4; ++u)
#pragma unroll
        for (int v = 0; v < 4; ++v) acc[u][v] = 0.f;

    float4 ayA[4], axA[4], wA4;
    float4 ayB[4], axB[4], wB4;

#define LOADF(AY, AX, W4, K4) do {                                          \
    W4 = *(const float4*)(sw2 + (K4) * 4);                                  \
    _Pragma("unroll") for (int u_ = 0; u_ < 4; ++u_)                        \
        AY[u_] = *(const float4*)(shy + (ty + 32 * u_) * STRD + (K4) * 4);  \
    _Pragma("unroll") for (int v_ = 0; v_ < 4; ++v_)                        \
        AX[v_] = *(const float4*)(shx + (tx + 16 * v_) * STRD + (K4) * 4);  \
} while (0)

#define FMAF(AY, AX, W4) do {                                               \
    _Pragma("unroll") for (int u_ = 0; u_ < 4; ++u_)                        \
    _Pragma("unroll") for (int v_ = 0; v_ < 4; ++v_) {                      \
        float t;                                                            \
        t = AY[u_].x + AX[v_].x; t = fmaxf(t, 0.f); acc[u_][v_] += t * W4.x;\
        t = AY[u_].y + AX[v_].y; t = fmaxf(t, 0.f); acc[u_][v_] += t * W4.y;\
        t = AY[u_].z + AX[v_].z; t = fmaxf(t, 0.f); acc[u_][v_] += t * W4.z;\
        t = AY[u_].w + AX[v_].w; t = fmaxf(t, 0.f); acc[u_][v_] += t * W4.w;\
    }                                                                       \
} while (0)

    LOADF(ayA, axA, wA4, 0);
    LOADF(ayB, axB, wB4, 1);
    FMAF(ayA, axA, wA4); LOADF(ayA, axA, wA4, 2);
    FMAF(ayB, axB, wB4); LOADF(ayB, axB, wB4, 3);
    FMAF(ayA, axA, wA4); LOADF(ayA, axA, wA4, 4);
    FMAF(ayB, axB, wB4); LOADF(ayB, axB, wB4, 5);
    FMAF(ayA, axA, wA4); LOADF(ayA, axA, wA4, 6);
    FMAF(ayB, axB, wB4); LOADF(ayB, axB, wB4, 7);
    FMAF(ayA, axA, wA4); LOADF(ayA, axA, wA4, 8);
    FMAF(ayB, axB, wB4); LOADF(ayB, axB, wB4, 9);
    FMAF(ayA, axA, wA4);
    FMAF(ayB, axB, wB4);

#undef LOADF
#undef FMAF

    const float b2v = b2p[0];
    const float c1  = b2v - 1.f;
    float sumE = 0.f, sumT = 0.f;
#pragma unroll
    for (int u = 0; u < 4; ++u)
#pragma unroll
        for (int v = 0; v < 4; ++v) {
            int gi = i0 + ty + 32 * u;
            int gj = j0 + tx + 16 * v;
            float val = acc[u][v];
            if (gi == gj) sumT += val + b2v;
            sumE += __expf(val + c1);
        }

#pragma unroll
    for (int off = 32; off > 0; off >>= 1) {
        sumE += __shfl_down(sumE, off);
        sumT += __shfl_down(sumT, off);
    }
    int wid = tid >> 6;                     // 0..7
    if ((tid & 63) == 0) { red[wid] = sumE; red[8 + wid] = sumT; }
    __syncthreads();
    if (tid == 0) {
        float e = 0.f, t = 0.f;
#pragma unroll
        for (int qq = 0; qq < 8; ++qq) { e += red[qq]; t += red[8 + qq]; }
        int bidp = blockIdx.y * gridDim.x + blockIdx.x;   // 0..511
        pairE[bidp] = e;
        pairT[bidp] = t;
    }
}

// ---------------------------------------------------------------------------
// Kernel 3: reduce 512 block-partials -> lower_bound.  (verified)
// ---------------------------------------------------------------------------
__global__ __launch_bounds__(512) void k_fin(const float* __restrict__ pairE,
                                             const float* __restrict__ pairT,
                                             float* __restrict__ out) {
    __shared__ float red[16];
    const int tid = threadIdx.x;
    float e = pairE[tid];
    float t = pairT[tid];
#pragma unroll
    for (int off = 32; off > 0; off >>= 1) {
        e += __shfl_down(e, off);
        t += __shfl_down(t, off);
    }
    int wid = tid >> 6;
    if ((tid & 63) == 0) { red[wid] = e; red[8 + wid] = t; }
    __syncthreads();
    if (tid == 0) {
        float se = 0.f, st = 0.f;
#pragma unroll
        for (int qq = 0; qq < 8; ++qq) { se += red[qq]; st += red[8 + qq]; }
        const float invN = 1.0f / (float)NROWS;
        out[0] = st * invN - se * invN * invN;
    }
}

extern "C" void kernel_launch(void* const* d_in, const int* in_sizes, int n_in,
                              void* d_out, int out_size, void* d_ws, size_t ws_size,
                              hipStream_t stream) {
    const float* x  = (const float*)d_in[0];
    const float* y  = (const float*)d_in[1];
    const float* W1 = (const float*)d_in[2];
    const float* b1 = (const float*)d_in[3];
    const float* W2 = (const float*)d_in[4];
    const float* b2 = (const float*)d_in[5];
    float* out = (float*)d_out;

    float* wsf   = (float*)d_ws;
    float* hxb   = wsf;                  // 2048*40, b1 folded in
    float* hy    = hxb + HN;             // 2048*40
    float* pairE = hy + HN;              // 512
    float* pairT = pairE + 512;          // 512

    k_proj<<<2048, 256, 0, stream>>>(x, y, W1, b1, hxb, hy);
    k_pair<<<dim3(NROWS / BI, NROWS / BJ), 512, 0, stream>>>(hxb, hy, W2, b2, pairE, pairT);
    k_fin<<<1, 512, 0, stream>>>(pairE, pairT, out);
}

// Round 16
// 92.400 us; speedup vs baseline: 1.0212x; 1.0212x over previous
//
#include <hip/hip_runtime.h>

#define NROWS 2048
#define KDIM  768
#define L     40
#define HN    (NROWS * L)   // 81920 floats per h matrix

#define OPB   20    // o per block (40 / 2 o-groups)
#define RPB   16    // rows per block
#define SEGS  32    // k-segments per row (24 k each)
#define SF4   6     // float4 per seg
#define SP4   7     // padded seg stride in LDS f4

// ---------------------------------------------------------------------------
// Kernel 1 (v9, R14-verified 92.0us total -- session best; resubmitted after
// R15's 8-wave experiment regressed to 94.4).
// Session conclusion: proj executes inside a fixed ~36-40us first-touch
// window that follows the harness's 256MiB poison-fill. The window is
// invariant to: staging (reg/L1/LDS), occupancy (1-8 w/SIMD; 4 is best),
// XCD swizzle, burst volume (13-123MB), and warm-up kernels (the R11 warmer
// simply absorbed the window itself). 512-thr blocks (16r x 32s), 512
// blocks = 2/CU, 4 waves/SIMD; W tile 20x768 staged padded; XCD grouping.
// ---------------------------------------------------------------------------
__global__ __launch_bounds__(512, 4) void k_proj(const float* __restrict__ x,
                                                 const float* __restrict__ y,
                                                 const float* __restrict__ W1,
                                                 const float* __restrict__ b1,
                                                 float* __restrict__ hxb,
                                                 float* __restrict__ hy) {
    const int bid = blockIdx.x;          // 0..511
    const int c   = bid & 7;             // XCD (round-robin mapping)
    const int m   = bid >> 3;            // 0..63
    const int j   = m & 3;               // replica: og*2+which
    const int q   = m >> 2;              // 0..15
    const int rb  = q * 8 + c;           // rowblock 0..127
    const int og    = j >> 1;            // 0..1
    const int which = j & 1;

    const float* __restrict__ A = which ? y : x;
    const int tid = threadIdx.x;
    const int s   = tid & 31;            // 0..31 k-segment (24 k each)
    const int r   = tid >> 5;            // 0..15 row within block
    const int row0 = rb * RPB;
    const int o0   = og * OPB;

    __shared__ float4 wlds[OPB * SEGS * SP4];   // 4480 f4 = 71.7 KB

    // ---- issue A loads first ----
    const float4* arow = (const float4*)(A + (size_t)(row0 + r) * KDIM) + s * SF4;
    float4 a[SF4];
#pragma unroll
    for (int jj = 0; jj < SF4; ++jj) a[jj] = arow[jj];

    // ---- stage W tile (20 rows x 192 f4, padded seg layout) ----
    const float4* W1f4 = (const float4*)W1;          // 384 f4 per W1 row
    for (int i = tid; i < OPB * 192; i += 512) {
        int ol = i / 192, qq = i - ol * 192;
        int ss = qq / SF4, jj = qq - ss * SF4;
        wlds[(ol * SEGS + ss) * SP4 + jj] =
            W1f4[(size_t)(o0 + ol) * 384 + which * 192 + qq];
    }
    __syncthreads();

    // ---- compute: per o, 6 broadcast LDS f4 + 24 FMA ----
    float acc[OPB];
#pragma unroll
    for (int ol = 0; ol < OPB; ++ol) {
        const float4* wp = &wlds[(ol * SEGS + s) * SP4];
        float sacc = 0.f;
#pragma unroll
        for (int jj = 0; jj < SF4; ++jj) {
            float4 w = wp[jj];
            sacc += a[jj].x * w.x + a[jj].y * w.y
                  + a[jj].z * w.z + a[jj].w * w.w;
        }
        acc[ol] = sacc;
    }

    // ---- cross-seg reduce via LDS: red[(ss*20+ol)*21 + rr] ----
    __syncthreads();
    float* red = (float*)wlds;                  // 32*20*21 = 13440 fl = 53.8 KB
#pragma unroll
    for (int ol = 0; ol < OPB; ++ol)
        red[(s * OPB + ol) * 21 + r] = acc[ol];
    __syncthreads();

    if (tid < RPB * OPB) {                       // 320 outputs
        int rr = tid / OPB, ol = tid - rr * OPB;
        float v = 0.f;
#pragma unroll
        for (int ss = 0; ss < SEGS; ++ss)
            v += red[(ss * OPB + ol) * 21 + rr];
        int o = o0 + ol;
        if (!which) {
            hxb[(size_t)(row0 + rr) * L + o] = v + b1[o];
        } else {
            hy[(size_t)(row0 + rr) * L + o] = v;
        }
    }
}

// ---------------------------------------------------------------------------
// Kernel 2: pairwise sum of exp(T_ij - 1) + diagonal T0 sum.  (verified)
// ---------------------------------------------------------------------------
#define BI 128
#define BJ 64
#define STRD 44

__global__ __launch_bounds__(512, 4) void k_pair(const float* __restrict__ hxb,
                                                 const float* __restrict__ hy,
                                                 const float* __restrict__ W2,
                                                 const float* __restrict__ b2p,
                                                 float* __restrict__ pairE,
                                                 float* __restrict__ pairT) {
    __shared__ float shy[BI * STRD];
    __shared__ float shx[BJ * STRD];
    __shared__ float sw2[STRD];
    __shared__ float red[16];

    const int tid = threadIdx.x;
    const int i0 = blockIdx.x * BI;
    const int j0 = blockIdx.y * BJ;

    for (int idx = tid; idx < BI * 10; idx += 512) {
        int rr = idx / 10, cc = idx - rr * 10;
        float4 v = ((const float4*)(hy + (size_t)i0 * L))[idx];
        *(float4*)(shy + rr * STRD + cc * 4) = v;
    }
    for (int idx = tid; idx < BJ * 10; idx += 512) {
        int rr = idx / 10, cc = idx - rr * 10;
        float4 v = ((const float4*)(hxb + (size_t)j0 * L))[idx];
        *(float4*)(shx + rr * STRD + cc * 4) = v;
    }
    if (tid < 10) ((float4*)sw2)[tid] = ((const float4*)W2)[tid];
    __syncthreads();

    const int tx = tid & 15, ty = tid >> 4;   // ty 0..31

    float acc[4][4];
#pragma unroll
    for (int u = 0; u < 4; ++u)
#pragma unroll
        for (int v = 0; v < 4; ++v) acc[u][v] = 0.f;

    float4 ayA[4], axA[4], wA4;
    float4 ayB[4], axB[4], wB4;

#define LOADF(AY, AX, W4, K4) do {                                          \
    W4 = *(const float4*)(sw2 + (K4) * 4);                                  \
    _Pragma("unroll") for (int u_ = 0; u_ < 4; ++u_)                        \
        AY[u_] = *(const float4*)(shy + (ty + 32 * u_) * STRD + (K4) * 4);  \
    _Pragma("unroll") for (int v_ = 0; v_ < 4; ++v_)                        \
        AX[v_] = *(const float4*)(shx + (tx + 16 * v_) * STRD + (K4) * 4);  \
} while (0)

#define FMAF(AY, AX, W4) do {                                               \
    _Pragma("unroll") for (int u_ = 0; u_ < 4; ++u_)                        \
    _Pragma("unroll") for (int v_ = 0; v_ < 4; ++v_) {                      \
        float t;                                                            \
        t = AY[u_].x + AX[v_].x; t = fmaxf(t, 0.f); acc[u_][v_] += t * W4.x;\
        t = AY[u_].y + AX[v_].y; t = fmaxf(t, 0.f); acc[u_][v_] += t * W4.y;\
        t = AY[u_].z + AX[v_].z; t = fmaxf(t, 0.f); acc[u_][v_] += t * W4.z;\
        t = AY[u_].w + AX[v_].w; t = fmaxf(t, 0.f); acc[u_][v_] += t * W4.w;\
    }                                                                       \
} while (0)

    LOADF(ayA, axA, wA4, 0);
    LOADF(ayB, axB, wB4, 1);
    FMAF(ayA, axA, wA4); LOADF(ayA, axA, wA4, 2);
    FMAF(ayB, axB, wB4); LOADF(ayB, axB, wB4, 3);
    FMAF(ayA, axA, wA4); LOADF(ayA, axA, wA4, 4);
    FMAF(ayB, axB, wB4); LOADF(ayB, axB, wB4, 5);
    FMAF(ayA, axA, wA4); LOADF(ayA, axA, wA4, 6);
    FMAF(ayB, axB, wB4); LOADF(ayB, axB, wB4, 7);
    FMAF(ayA, axA, wA4); LOADF(ayA, axA, wA4, 8);
    FMAF(ayB, axB, wB4); LOADF(ayB, axB, wB4, 9);
    FMAF(ayA, axA, wA4);
    FMAF(ayB, axB, wB4);

#undef LOADF
#undef FMAF

    const float b2v = b2p[0];
    const float c1  = b2v - 1.f;
    float sumE = 0.f, sumT = 0.f;
#pragma unroll
    for (int u = 0; u < 4; ++u)
#pragma unroll
        for (int v = 0; v < 4; ++v) {
            int gi = i0 + ty + 32 * u;
            int gj = j0 + tx + 16 * v;
            float val = acc[u][v];
            if (gi == gj) sumT += val + b2v;
            sumE += __expf(val + c1);
        }

#pragma unroll
    for (int off = 32; off > 0; off >>= 1) {
        sumE += __shfl_down(sumE, off);
        sumT += __shfl_down(sumT, off);
    }
    int wid = tid >> 6;                     // 0..7
    if ((tid & 63) == 0) { red[wid] = sumE; red[8 + wid] = sumT; }
    __syncthreads();
    if (tid == 0) {
        float e = 0.f, t = 0.f;
#pragma unroll
        for (int qq = 0; qq < 8; ++qq) { e += red[qq]; t += red[8 + qq]; }
        int bidp = blockIdx.y * gridDim.x + blockIdx.x;   // 0..511
        pairE[bidp] = e;
        pairT[bidp] = t;
    }
}

// ---------------------------------------------------------------------------
// Kernel 3: reduce 512 block-partials -> lower_bound.  (verified)
// ---------------------------------------------------------------------------
__global__ __launch_bounds__(512) void k_fin(const float* __restrict__ pairE,
                                             const float* __restrict__ pairT,
                                             float* __restrict__ out) {
    __shared__ float red[16];
    const int tid = threadIdx.x;
    float e = pairE[tid];
    float t = pairT[tid];
#pragma unroll
    for (int off = 32; off > 0; off >>= 1) {
        e += __shfl_down(e, off);
        t += __shfl_down(t, off);
    }
    int wid = tid >> 6;
    if ((tid & 63) == 0) { red[wid] = e; red[8 + wid] = t; }
    __syncthreads();
    if (tid == 0) {
        float se = 0.f, st = 0.f;
#pragma unroll
        for (int qq = 0; qq < 8; ++qq) { se += red[qq]; st += red[8 + qq]; }
        const float invN = 1.0f / (float)NROWS;
        out[0] = st * invN - se * invN * invN;
    }
}

extern "C" void kernel_launch(void* const* d_in, const int* in_sizes, int n_in,
                              void* d_out, int out_size, void* d_ws, size_t ws_size,
                              hipStream_t stream) {
    const float* x  = (const float*)d_in[0];
    const float* y  = (const float*)d_in[1];
    const float* W1 = (const float*)d_in[2];
    const float* b1 = (const float*)d_in[3];
    const float* W2 = (const float*)d_in[4];
    const float* b2 = (const float*)d_in[5];
    float* out = (float*)d_out;

    float* wsf   = (float*)d_ws;
    float* hxb   = wsf;                  // 2048*40, b1 folded in
    float* hy    = hxb + HN;             // 2048*40
    float* pairE = hy + HN;              // 512
    float* pairT = pairE + 512;          // 512

    k_proj<<<512, 512, 0, stream>>>(x, y, W1, b1, hxb, hy);
    k_pair<<<dim3(NROWS / BI, NROWS / BJ), 512, 0, stream>>>(hxb, hy, W2, b2, pairE, pairT);
    k_fin<<<1, 512, 0, stream>>>(pairE, pairT, out);
}